// Round 12
// baseline (847.388 us; speedup 1.0000x reference)
//
#include <hip/hip_runtime.h>

#define T_TOK 8192
#define HDIM  2048
#define NEXP  32
#define IDIM  1024

#define BM 128
#define BN 128
#define CAPO (T_TOK*2 + NEXP*128)   // 20480 rows, 128-align (fallback path)
#define CAPN (T_TOK*2 + NEXP*256)   // 24576 rows, 256-align (8-phase path)
#define MAX_RT (CAPO/128)
#define RT256 (CAPN/256)            // 96
#define CVB 8192
#define NTB 2048

typedef __attribute__((ext_vector_type(8))) short bh8;
typedef __attribute__((ext_vector_type(4))) float f4;

__device__ __forceinline__ unsigned short f2bf(float f) {
    unsigned u = __builtin_bit_cast(unsigned, f);
    u += 0x7FFFu + ((u >> 16) & 1u);
    return (unsigned short)(u >> 16);
}
__device__ __forceinline__ float bf2f(unsigned short s) {
    return __builtin_bit_cast(float, (unsigned)s << 16);
}
// proven swizzle (rounds 1-2): 128B LDS rows, byte ^= (row&7)<<4
__device__ __forceinline__ int swz(int row, int kb) {
    return row * 128 + (kb ^ ((row & 7) << 4));
}
__device__ __forceinline__ void gload16(const void* g, void* l) {
    __builtin_amdgcn_global_load_lds(
        (const __attribute__((address_space(1))) unsigned int*)g,
        (__attribute__((address_space(3))) unsigned int*)l,
        16, 0, 0);
}

// ---------------- routing ----------------
__device__ __forceinline__ void top2(const float* __restrict__ l,
                                     int& b1, float& v1, int& b2, float& v2) {
    v1 = -1e30f; b1 = 0;
#pragma unroll
    for (int e = 0; e < NEXP; ++e) { float v = l[e]; if (v > v1) { v1 = v; b1 = e; } }
    v2 = -1e30f; b2 = 0;
#pragma unroll
    for (int e = 0; e < NEXP; ++e) { if (e == b1) continue; float v = l[e]; if (v > v2) { v2 = v; b2 = e; } }
}

__global__ void route_count_kernel(const float* __restrict__ logits, int* __restrict__ counts) {
    int t = blockIdx.x * blockDim.x + threadIdx.x;
    if (t >= T_TOK) return;
    int b1, b2; float v1, v2;
    top2(logits + (size_t)t * NEXP, b1, v1, b2, v2);
    atomicAdd(&counts[b1], 1);
    atomicAdd(&counts[b2], 1);
}

__global__ void offsets_kernel(const int* __restrict__ counts, int* __restrict__ offs, int align) {
    if (threadIdx.x == 0) {
        int o = 0;
        for (int e = 0; e < NEXP; ++e) { offs[e] = o; o += (counts[e] + align - 1) & ~(align - 1); }
        offs[NEXP] = o;
    }
}

__global__ void route_scatter_kernel(const float* __restrict__ logits,
                                     const float* __restrict__ scale,
                                     const int* __restrict__ offs,
                                     int* __restrict__ cursor,
                                     int* __restrict__ row_tok,
                                     float* __restrict__ row_w) {
    int t = blockIdx.x * blockDim.x + threadIdx.x;
    if (t >= T_TOK) return;
    int b1, b2; float v1, v2;
    top2(logits + (size_t)t * NEXP, b1, v1, b2, v2);
    float e2 = expf(v2 - v1);
    float inv = 1.0f / (1.0f + e2);
    float w1 = scale[b1] * inv;
    float w2 = scale[b2] * e2 * inv;
    int p1 = offs[b1] + atomicAdd(&cursor[b1], 1);
    row_tok[p1] = t; row_w[p1] = w1;
    int p2 = offs[b2] + atomicAdd(&cursor[b2], 1);
    row_tok[p2] = t; row_w[p2] = w2;
}

// ---------------- prep (r11, frozen) ----------------
__device__ __forceinline__ void half_dma(const float* __restrict__ in, int K, int N,
                                         int e, int k0, int n0, char* ldsH, int t) {
    const char* src = (const char*)(in + (size_t)e * K * N + (size_t)k0 * N + n0);
    int w = t >> 6;
#pragma unroll
    for (int i = 0; i < 8; ++i) {
        int c = i * 256 + t;
        int k = c >> 5;
        int cc = (c & 31) ^ (((k >> 3) & 7) << 2);
        gload16(src + (size_t)k * N * 4 + (size_t)cc * 16, ldsH + i * 4096 + w * 1024);
    }
}
__device__ __forceinline__ void half_store(unsigned short* __restrict__ out, int K, int N,
                                           int e, int k0, int n0, const char* ldsH, int t) {
    unsigned short* dst = out + (size_t)e * K * N + (size_t)n0 * K + k0;
    int kg = t & 7, nb = t >> 3;
#pragma unroll
    for (int p = 0; p < 4; ++p) {
        int n = nb + 32 * p;
        bh8 v;
#pragma unroll
        for (int j = 0; j < 8; ++j) {
            int kl = 8 * kg + j;
            int boff = kl * 512 + ((((n >> 2) ^ ((kg & 7) << 2)) << 4)) + (n & 3) * 4;
            v[j] = (short)f2bf(*(const float*)(ldsH + boff));
        }
        *(bh8*)(dst + (size_t)n * K + 8 * kg) = v;
    }
}
__device__ __forceinline__ void tile_params(int g,
                                            const float* wg, const float* wu, const float* wd,
                                            unsigned short* wgT, unsigned short* wuT, unsigned short* wdT,
                                            const float*& in, unsigned short*& out,
                                            int& K, int& N, int& e, int& k0, int& n0) {
    int mat = g >> 12;
    int loc = g & 4095;
    e = loc >> 7;
    int tl = loc & 127;
    if (mat == 2) { in = wd; out = wdT; K = IDIM; N = HDIM; k0 = (tl >> 4) << 7; n0 = (tl & 15) << 7; }
    else if (mat == 1) { in = wu; out = wuT; K = HDIM; N = IDIM; k0 = (tl >> 3) << 7; n0 = (tl & 7) << 7; }
    else { in = wg; out = wgT; K = HDIM; N = IDIM; k0 = (tl >> 3) << 7; n0 = (tl & 7) << 7; }
}
__global__ void prep_all(const float* __restrict__ hs, unsigned short* __restrict__ hsb,
                         const float* __restrict__ wg, unsigned short* __restrict__ wgT,
                         const float* __restrict__ wu, unsigned short* __restrict__ wuT,
                         const float* __restrict__ wd, unsigned short* __restrict__ wdT,
                         int nTiles) {
    __shared__ float lds4[16384];
    int b = blockIdx.x;
    int t = threadIdx.x;
    if (b < CVB) {
        size_t i = ((size_t)b * 256 + t) * 8;
        float4 a = *(const float4*)(hs + i);
        float4 c = *(const float4*)(hs + i + 4);
        bh8 v;
        v[0] = (short)f2bf(a.x); v[1] = (short)f2bf(a.y);
        v[2] = (short)f2bf(a.z); v[3] = (short)f2bf(a.w);
        v[4] = (short)f2bf(c.x); v[5] = (short)f2bf(c.y);
        v[6] = (short)f2bf(c.z); v[7] = (short)f2bf(c.w);
        *(bh8*)(hsb + i) = v;
        return;
    }
    int tb = b - CVB;
    char* L0 = (char*)lds4;
    char* L1 = L0 + 32768;
    int nq = nTiles / NTB;
    {
        const float* in; unsigned short* o; int K, N, e, k0, n0;
        tile_params(tb, wg, wu, wd, wgT, wuT, wdT, in, o, K, N, e, k0, n0);
        half_dma(in, K, N, e, k0, n0, L0, t);
    }
    __syncthreads();
    int cur = 0;
    for (int q = 0; q < nq; ++q) {
        const float* in; unsigned short* o; int K, N, e, k0, n0;
        tile_params(tb + q * NTB, wg, wu, wd, wgT, wuT, wdT, in, o, K, N, e, k0, n0);
#pragma unroll
        for (int hh = 0; hh < 2; ++hh) {
            int nq2 = q, nh = hh + 1;
            if (nh == 2) { nq2 = q + 1; nh = 0; }
            if (nq2 < nq) {
                const float* in2; unsigned short* o2; int K2, N2, e2, k02, n02;
                tile_params(tb + nq2 * NTB, wg, wu, wd, wgT, wuT, wdT, in2, o2, K2, N2, e2, k02, n02);
                half_dma(in2, K2, N2, e2, k02 + nh * 64, n02, cur ? L0 : L1, t);
            }
            half_store(o, K, N, e, k0 + hh * 64, n0, cur ? L1 : L0, t);
            __syncthreads();
            cur ^= 1;
        }
    }
}
__global__ void transpose_wd_kernel(const float* __restrict__ wd, unsigned short* __restrict__ wdT) {
    __shared__ float lds4[16384];
    int tb = blockIdx.x, t = threadIdx.x;
    char* L0 = (char*)lds4;
    char* L1 = L0 + 32768;
    auto prm = [&](int g, int& e, int& k0, int& n0) {
        e = g >> 7; int tl = g & 127;
        k0 = (tl >> 4) << 7; n0 = (tl & 15) << 7;
    };
    int e, k0, n0;
    prm(tb, e, k0, n0);
    half_dma(wd, IDIM, HDIM, e, k0, n0, L0, t);
    __syncthreads();
    int cur = 0;
    for (int q = 0; q < 2; ++q) {
        int eq, kq, nq0;
        prm(tb + q * NTB, eq, kq, nq0);
#pragma unroll
        for (int hh = 0; hh < 2; ++hh) {
            int q2 = q, nh = hh + 1;
            if (nh == 2) { q2 = q + 1; nh = 0; }
            if (q2 < 2) {
                int e2, k2, n2;
                prm(tb + q2 * NTB, e2, k2, n2);
                half_dma(wd, IDIM, HDIM, e2, k2 + nh * 64, n2, cur ? L0 : L1, t);
            }
            half_store(wdT, IDIM, HDIM, eq, kq + hh * 64, nq0, cur ? L1 : L0, t);
            __syncthreads();
            cur ^= 1;
        }
    }
}

// ============ 8-phase 256x256 GEMM template (m201 port) ============
// MODE 0: U = X@WuT^T -> raw bf16 (swizzled rows)
// MODE 1: act = gelu(X@WgT^T) * U -> bf16 (swizzled rows)
// MODE 2: out[tok] += w * (act@WdT^T) fp32 atomic
// 512 thr = 8 waves (2M x 4N); wave tile 128x64; acc 8x4 f4 = 128 VGPR.
// LDS 128KB: buf{0,1} x {Ah0,Ah1,Bh0,Bh1} x 16KB. Per phase: stage 1 half(t+1),
// vmcnt(2)@phase0, s_barrier, 8 ds_read_b128, lgkmcnt(0)+sched_barrier,
// setprio(1), 16 MFMA, setprio(0), s_barrier.
template<int MODE>
__launch_bounds__(512, 1)
__global__ void gemm8p(const unsigned short* __restrict__ Abase,
                       const unsigned short* __restrict__ Bw,
                       const int* __restrict__ offs,
                       const int* __restrict__ row_tok,
                       const float* __restrict__ row_w,
                       const unsigned short* __restrict__ uin,
                       unsigned short* __restrict__ outb,
                       float* __restrict__ outf) {
    constexpr int K   = (MODE == 2) ? IDIM : HDIM;
    constexpr int NT  = K / 64;
    constexpr int N0  = (MODE == 2) ? HDIM : IDIM;
    constexpr int NTL = N0 / 256;

    __shared__ char lds[131072];

    int bid = blockIdx.x;
    int rt = bid / NTL, nt = bid % NTL;
    if (rt * 256 >= offs[NEXP]) return;
    int e = 0;
    while (offs[e + 1] <= rt * 256) e++;

    int t = threadIdx.x, l = t & 63, w = t >> 6;
    int wm = w >> 2, wn = w & 3;

    unsigned srcx = ((l & 7) * 16) ^ ((l >> 3) << 4);
    unsigned aoff[4];
#pragma unroll
    for (int j = 0; j < 4; ++j) {
        int r = rt * 256 + j * 64 + (t >> 3);
        if (MODE == 2) {
            aoff[j] = (unsigned)r * (K * 2) + (l & 7) * 16;  // act pre-swizzled: linear src
        } else {
            int tok = row_tok[r];
            if (tok < 0) tok = 0;
            aoff[j] = (unsigned)tok * (K * 2) + srcx;
        }
    }
    unsigned boff[4];
#pragma unroll
    for (int j = 0; j < 4; ++j) {
        unsigned br = (unsigned)e * N0 + nt * 256 + j * 64 + (t >> 3);
        boff[j] = br * (K * 2) + srcx;
    }
    const char* Ac = (const char*)Abase;
    const char* Bc = (const char*)Bw;

    f4 acc[8][4];
#pragma unroll
    for (int mi = 0; mi < 8; ++mi)
#pragma unroll
        for (int ni = 0; ni < 4; ++ni) acc[mi][ni] = (f4)0.0f;

    // stage half H of tile KT1 into buffer NB (2 gload16/thread)
#define STG(H, NB, KT1) {                                                    \
    size_t kby_ = (size_t)(KT1) * 128;                                       \
    _Pragma("unroll")                                                        \
    for (int i_ = 0; i_ < 2; ++i_) {                                         \
        const char* s_ = ((H) < 2) ? (Ac + (size_t)aoff[(H) * 2 + i_] + kby_)\
                                   : (Bc + (size_t)boff[((H) - 2) * 2 + i_] + kby_); \
        gload16(s_, lds + (NB) * 65536 + (H) * 16384 + i_ * 8192 + w * 1024);\
    } }

    // prologue: full tile 0 into buf0
    STG(0, 0, 0) STG(1, 0, 0) STG(2, 0, 0) STG(3, 0, 0)
    __syncthreads();

    int kb0 = (l >> 4) << 4;

#define PH(P) {                                                              \
    STG(P, nb, ktn)                                                          \
    if ((P) == 0) asm volatile("s_waitcnt vmcnt(2)" ::: "memory");           \
    __builtin_amdgcn_s_barrier();                                            \
    const char* Ab_ = lds + cb * 65536 + wm * 16384;                         \
    const char* Bb_ = lds + cb * 65536 + 32768 + (wn >> 1) * 16384;          \
    int kb_ = ((P) >> 1) * 64 + kb0;                                         \
    bh8 aA[4], bB[4];                                                        \
    _Pragma("unroll")                                                        \
    for (int j_ = 0; j_ < 4; ++j_)                                           \
        aA[j_] = *(const bh8*)(Ab_ + swz(((P & 1) * 4 + j_) * 16 + (l & 15), kb_)); \
    _Pragma("unroll")                                                        \
    for (int n_ = 0; n_ < 4; ++n_)                                           \
        bB[n_] = *(const bh8*)(Bb_ + swz((wn & 1) * 64 + n_ * 16 + (l & 15), kb_)); \
    asm volatile("s_waitcnt lgkmcnt(0)" ::: "memory");                       \
    __builtin_amdgcn_sched_barrier(0);                                       \
    __builtin_amdgcn_s_setprio(1);                                           \
    _Pragma("unroll")                                                        \
    for (int j_ = 0; j_ < 4; ++j_)                                           \
        _Pragma("unroll")                                                    \
        for (int n_ = 0; n_ < 4; ++n_)                                       \
            acc[(P & 1) * 4 + j_][n_] = __builtin_amdgcn_mfma_f32_16x16x32_bf16( \
                aA[j_], bB[n_], acc[(P & 1) * 4 + j_][n_], 0, 0, 0);         \
    __builtin_amdgcn_s_setprio(0);                                           \
    __builtin_amdgcn_s_barrier();                                            \
}

    for (int kt = 0; kt < NT; ++kt) {
        int cb = kt & 1;
        int nb = cb ^ 1;
        int ktn = (kt + 1 < NT) ? kt + 1 : 0;   // last tile: dead-stage tile 0 (keeps vmcnt uniform)
        PH(0) PH(1) PH(2) PH(3)
    }
#undef PH
#undef STG

    // epilogue
#pragma unroll
    for (int mi = 0; mi < 8; ++mi) {
#pragma unroll
        for (int i = 0; i < 4; ++i) {
            int gr = rt * 256 + wm * 128 + mi * 16 + ((l >> 4) << 2) + i;
            if (MODE == 2) {
                int tok = row_tok[gr];
                if (tok < 0) continue;
                float wgt = row_w[gr];
                float* op = outf + (size_t)tok * HDIM + nt * 256 + wn * 64 + (l & 15);
#pragma unroll
                for (int ni = 0; ni < 4; ++ni)
                    atomicAdd(op + ni * 16, acc[mi][ni][i] * wgt);
            } else {
                size_t rowbase = (size_t)gr * (N0 * 2);
                int rs = (gr & 7) << 4;
#pragma unroll
                for (int ni = 0; ni < 4; ++ni) {
                    int col = nt * 256 + wn * 64 + ni * 16 + (l & 15);
                    size_t addr = rowbase + (size_t)((col * 2) ^ rs);
                    if (MODE == 0) {
                        *(unsigned short*)((char*)outb + addr) = f2bf(acc[mi][ni][i]);
                    } else {
                        float uu = bf2f(*(const unsigned short*)((const char*)uin + addr));
                        float g = acc[mi][ni][i];
                        float gl = 0.5f * g * (1.0f + erff(g * 0.70710678118654752f));
                        *(unsigned short*)((char*)outb + addr) = f2bf(gl * uu);
                    }
                }
            }
        }
    }
}

// ============ fallback GEMMs (r2-proven bodies) ============
__launch_bounds__(256, 2)
__global__ void gemm1n_kernel(const unsigned short* __restrict__ hsb,
                              const unsigned short* __restrict__ wgT,
                              const unsigned short* __restrict__ wuT,
                              const int* __restrict__ offs,
                              const int* __restrict__ row_tok,
                              unsigned short* __restrict__ act) {
    __shared__ char lds[49152];
    char* Xb = lds;
    char* Gb = lds + 16384;
    char* Ub = lds + 32768;

    int rt = blockIdx.x >> 3;
    int nt = blockIdx.x & 7;
    int total = offs[NEXP];
    if (rt * BM >= total) return;
    int e = 0;
    while (offs[e + 1] <= rt * BM) e++;

    int tid = threadIdx.x, l = tid & 63, wv = tid >> 6;
    int wm = wv >> 1, wn = wv & 1;
    unsigned srcChunk = ((l & 7) * 16) ^ ((l >> 3) << 4);

    unsigned xoff[4], goff[4];
#pragma unroll
    for (int i = 0; i < 4; ++i) {
        int r = i * 32 + wv * 8 + (l >> 3);
        int tok = row_tok[rt * BM + r];
        if (tok < 0) tok = 0;
        xoff[i] = (unsigned)tok * (HDIM * 2) + srcChunk;
        unsigned wrow = (unsigned)e * IDIM + nt * BN + r;
        goff[i] = wrow * (HDIM * 2) + srcChunk;
    }

    f4 accG[4][4], accU[4][4];
#pragma unroll
    for (int mi = 0; mi < 4; ++mi)
#pragma unroll
        for (int ni = 0; ni < 4; ++ni) { accG[mi][ni] = (f4)0.0f; accU[mi][ni] = (f4)0.0f; }

    const char* hsc = (const char*)hsb;
    const char* wgc = (const char*)wgT;
    const char* wuc = (const char*)wuT;

    for (int kt = 0; kt < HDIM / 64; ++kt) {
        unsigned kby = kt * 128;
#pragma unroll
        for (int i = 0; i < 4; ++i)
            gload16(hsc + (size_t)xoff[i] + kby, Xb + i * 4096 + wv * 1024);
#pragma unroll
        for (int i = 0; i < 4; ++i)
            gload16(wgc + (size_t)goff[i] + kby, Gb + i * 4096 + wv * 1024);
#pragma unroll
        for (int i = 0; i < 4; ++i)
            gload16(wuc + (size_t)goff[i] + kby, Ub + i * 4096 + wv * 1024);
        __syncthreads();

#pragma unroll
        for (int ks = 0; ks < 2; ++ks) {
            int kb = ks * 64 + ((l >> 4) << 4);
            bh8 a[4], g[4], u[4];
#pragma unroll
            for (int mi = 0; mi < 4; ++mi)
                a[mi] = *(const bh8*)(Xb + swz(wm * 64 + mi * 16 + (l & 15), kb));
#pragma unroll
            for (int ni = 0; ni < 4; ++ni) {
                int nr = wn * 64 + ni * 16 + (l & 15);
                g[ni] = *(const bh8*)(Gb + swz(nr, kb));
                u[ni] = *(const bh8*)(Ub + swz(nr, kb));
            }
#pragma unroll
            for (int mi = 0; mi < 4; ++mi)
#pragma unroll
                for (int ni = 0; ni < 4; ++ni) {
                    accG[mi][ni] = __builtin_amdgcn_mfma_f32_16x16x32_bf16(a[mi], g[ni], accG[mi][ni], 0, 0, 0);
                    accU[mi][ni] = __builtin_amdgcn_mfma_f32_16x16x32_bf16(a[mi], u[ni], accU[mi][ni], 0, 0, 0);
                }
        }
        __syncthreads();
    }

    char* actc = (char*)act;
#pragma unroll
    for (int mi = 0; mi < 4; ++mi) {
#pragma unroll
        for (int i = 0; i < 4; ++i) {
            int r = rt * BM + wm * 64 + mi * 16 + ((l >> 4) << 2) + i;
            size_t rowbase = (size_t)r * (IDIM * 2);
            int rs = (r & 7) << 4;
#pragma unroll
            for (int ni = 0; ni < 4; ++ni) {
                int col = nt * BN + wn * 64 + ni * 16 + (l & 15);
                float gv = accG[mi][ni][i], uv = accU[mi][ni][i];
                float gl = 0.5f * gv * (1.0f + erff(gv * 0.70710678118654752f));
                *(unsigned short*)(actc + rowbase + ((col * 2) ^ rs)) = f2bf(gl * uv);
            }
        }
    }
}

__launch_bounds__(256, 2)
__global__ void gemm2n_kernel(const unsigned short* __restrict__ act,
                              const unsigned short* __restrict__ wdT,
                              const int* __restrict__ offs,
                              const int* __restrict__ row_tok,
                              const float* __restrict__ row_w,
                              float* __restrict__ out) {
    __shared__ char lds[49152];
    char* Xb = lds;
    char* Db = lds + 16384;

    int rt = blockIdx.x >> 3;
    int nt = blockIdx.x & 7;
    int total = offs[NEXP];
    if (rt * BM >= total) return;
    int e = 0;
    while (offs[e + 1] <= rt * BM) e++;

    int tid = threadIdx.x, l = tid & 63, wv = tid >> 6;
    int wm = wv >> 1, wn = wv & 1;
    unsigned srcChunk = ((l & 7) * 16) ^ ((l >> 3) << 4);

    unsigned aoff[4];
#pragma unroll
    for (int i = 0; i < 4; ++i) {
        int r = i * 32 + wv * 8 + (l >> 3);
        aoff[i] = (unsigned)(rt * BM + r) * (IDIM * 2) + (l & 7) * 16;
    }
    unsigned doff[8];
#pragma unroll
    for (int i = 0; i < 8; ++i) {
        int r = i * 32 + wv * 8 + (l >> 3);
        doff[i] = ((unsigned)e * HDIM + nt * 256 + r) * (IDIM * 2) + srcChunk;
    }

    f4 acc[4][8];
#pragma unroll
    for (int mi = 0; mi < 4; ++mi)
#pragma unroll
        for (int ni = 0; ni < 8; ++ni) acc[mi][ni] = (f4)0.0f;

    const char* actc = (const char*)act;
    const char* wdc = (const char*)wdT;

    for (int kt = 0; kt < IDIM / 64; ++kt) {
        unsigned kby = kt * 128;
#pragma unroll
        for (int i = 0; i < 4; ++i)
            gload16(actc + (size_t)aoff[i] + kby, Xb + i * 4096 + wv * 1024);
#pragma unroll
        for (int i = 0; i < 8; ++i)
            gload16(wdc + (size_t)doff[i] + kby, Db + i * 4096 + wv * 1024);
        __syncthreads();

#pragma unroll
        for (int ks = 0; ks < 2; ++ks) {
            int kb = ks * 64 + ((l >> 4) << 4);
            bh8 a[4], b[8];
#pragma unroll
            for (int mi = 0; mi < 4; ++mi)
                a[mi] = *(const bh8*)(Xb + swz(wm * 64 + mi * 16 + (l & 15), kb));
#pragma unroll
            for (int ni = 0; ni < 8; ++ni)
                b[ni] = *(const bh8*)(Db + swz(wn * 128 + ni * 16 + (l & 15), kb));
#pragma unroll
            for (int mi = 0; mi < 4; ++mi)
#pragma unroll
                for (int ni = 0; ni < 8; ++ni)
                    acc[mi][ni] = __builtin_amdgcn_mfma_f32_16x16x32_bf16(a[mi], b[ni], acc[mi][ni], 0, 0, 0);
        }
        __syncthreads();
    }

#pragma unroll
    for (int mi = 0; mi < 4; ++mi) {
#pragma unroll
        for (int i = 0; i < 4; ++i) {
            int r = rt * BM + wm * 64 + mi * 16 + ((l >> 4) << 2) + i;
            int tok = row_tok[r];
            if (tok < 0) continue;
            float w = row_w[r];
            float* op = out + (size_t)tok * HDIM + nt * 256 + wn * 128 + (l & 15);
#pragma unroll
            for (int ni = 0; ni < 8; ++ni)
                atomicAdd(op + ni * 16, acc[mi][ni][i] * w);
        }
    }
}

// ---------------- launch ----------------
// Full (8-phase) layout: hdr | row_tok CAPN*4 | row_w CAPN*4 | act CAPN*I*2 |
//   ubuf CAPN*I*2 | hsb T*H*2 | wgT | wuT | wdT  -> ~537 MB
// Mid fallback (r11): act CAPO*I*2 | hsb | wgT | wuT | wdT -> ~478 MB
// Low fallback: ... | wgT | wuT (wdT reuses wgT) -> ~344 MB

extern "C" void kernel_launch(void* const* d_in, const int* in_sizes, int n_in,
                              void* d_out, int out_size, void* d_ws, size_t ws_size,
                              hipStream_t stream) {
    const float* hs     = (const float*)d_in[0];
    const float* logits = (const float*)d_in[1];
    const float* scale  = (const float*)d_in[2];
    const float* wg     = (const float*)d_in[3];
    const float* wu     = (const float*)d_in[4];
    const float* wd     = (const float*)d_in[5];
    float* out = (float*)d_out;

    char* ws = (char*)d_ws;
    int*   counts  = (int*)ws;
    int*   cursor  = counts + 32;
    int*   offs    = cursor + 32;
    int*   row_tok = (int*)(ws + 512);
    float* row_w   = (float*)(ws + 512 + (size_t)CAPN * 4);

    size_t base  = 512 + (size_t)CAPN * 8;
    size_t actBN = (size_t)CAPN * IDIM * 2;
    size_t actBO = (size_t)CAPO * IDIM * 2;
    size_t hsB   = (size_t)T_TOK * HDIM * 2;
    size_t wTB   = (size_t)NEXP * IDIM * HDIM * 2;

    size_t needFull = base + 2 * actBN + hsB + 3 * wTB;
    size_t needMid  = base + actBO + hsB + 3 * wTB;

    hipMemsetAsync(counts, 0, 512, stream);
    hipMemsetAsync(row_tok, 0xFF, (size_t)CAPN * 4, stream);
    hipMemsetAsync(out, 0, (size_t)out_size * sizeof(float), stream);

    route_count_kernel<<<T_TOK / 256, 256, 0, stream>>>(logits, counts);

    if (ws_size >= needFull) {
        unsigned short* act  = (unsigned short*)(ws + base);
        unsigned short* ubuf = (unsigned short*)(ws + base + actBN);
        unsigned short* hsb  = (unsigned short*)(ws + base + 2 * actBN);
        unsigned short* wgT  = (unsigned short*)(ws + base + 2 * actBN + hsB);
        unsigned short* wuT  = (unsigned short*)(ws + base + 2 * actBN + hsB + wTB);
        unsigned short* wdT  = (unsigned short*)(ws + base + 2 * actBN + hsB + 2 * wTB);

        offsets_kernel<<<1, 64, 0, stream>>>(counts, offs, 256);
        route_scatter_kernel<<<T_TOK / 256, 256, 0, stream>>>(logits, scale, offs, cursor, row_tok, row_w);
        prep_all<<<CVB + NTB, 256, 0, stream>>>(hs, hsb, wg, wgT, wu, wuT, wd, wdT, 12288);
        gemm8p<0><<<RT256 * 4, 512, 0, stream>>>(hsb, wuT, offs, row_tok, row_w, nullptr, ubuf, nullptr);
        gemm8p<1><<<RT256 * 4, 512, 0, stream>>>(hsb, wgT, offs, row_tok, row_w, ubuf, act, nullptr);
        gemm8p<2><<<RT256 * 8, 512, 0, stream>>>(act, wdT, offs, row_tok, row_w, nullptr, nullptr, out);
    } else if (ws_size >= needMid) {
        unsigned short* act = (unsigned short*)(ws + base);
        unsigned short* hsb = (unsigned short*)(ws + base + actBO);
        unsigned short* wgT = (unsigned short*)(ws + base + actBO + hsB);
        unsigned short* wuT = (unsigned short*)(ws + base + actBO + hsB + wTB);
        unsigned short* wdT = (unsigned short*)(ws + base + actBO + hsB + 2 * wTB);

        offsets_kernel<<<1, 64, 0, stream>>>(counts, offs, 128);
        route_scatter_kernel<<<T_TOK / 256, 256, 0, stream>>>(logits, scale, offs, cursor, row_tok, row_w);
        prep_all<<<CVB + NTB, 256, 0, stream>>>(hs, hsb, wg, wgT, wu, wuT, wd, wdT, 12288);
        gemm1n_kernel<<<MAX_RT * 8, 256, 0, stream>>>(hsb, wgT, wuT, offs, row_tok, act);
        gemm2n_kernel<<<MAX_RT * 8, 256, 0, stream>>>(act, wdT, offs, row_tok, row_w, out);
    } else {
        unsigned short* act = (unsigned short*)(ws + base);
        unsigned short* hsb = (unsigned short*)(ws + base + actBO);
        unsigned short* wgT = (unsigned short*)(ws + base + actBO + hsB);
        unsigned short* wuT = (unsigned short*)(ws + base + actBO + hsB + wTB);

        offsets_kernel<<<1, 64, 0, stream>>>(counts, offs, 128);
        route_scatter_kernel<<<T_TOK / 256, 256, 0, stream>>>(logits, scale, offs, cursor, row_tok, row_w);
        prep_all<<<CVB + NTB, 256, 0, stream>>>(hs, hsb, wg, wgT, wu, wuT, nullptr, nullptr, 8192);
        gemm1n_kernel<<<MAX_RT * 8, 256, 0, stream>>>(hsb, wgT, wuT, offs, row_tok, act);
        transpose_wd_kernel<<<NTB, 256, 0, stream>>>(wd, wgT);
        gemm2n_kernel<<<MAX_RT * 8, 256, 0, stream>>>(act, wgT, offs, row_tok, row_w, out);
    }
}